// Round 4
// baseline (93.273 us; speedup 1.0000x reference)
//
#include <hip/hip_runtime.h>

#define NEGV -1.0e12f
constexpr int B = 16, C = 384, Q = 64, D = 2048;
constexpr int IMG = 15360;   // shorts per 64-k B-image (30720 B = 30 KB-chunks)
constexpr int PITCH = 72;    // shorts per row (144 B, 16B-aligned, low conflict)
constexpr int NIMG = 32;     // images per batch (D/64)
constexpr int MT = 64;       // c-rows per k_score block
constexpr int SP = 224;      // S3 padded col pitch (195 used)

typedef __attribute__((ext_vector_type(8))) short s16x8;
typedef __attribute__((ext_vector_type(4))) float f32x4;
typedef __attribute__((ext_vector_type(4))) unsigned u32x4;

__device__ __forceinline__ unsigned pkbf(float lo, float hi) {
  unsigned ulo = __builtin_bit_cast(unsigned, lo);
  unsigned uhi = __builtin_bit_cast(unsigned, hi);
  return (uhi & 0xFFFF0000u) | (ulo >> 16);
}

// ---------------- kernel 0: pre-pack B images into ws -----------------------
// Per (b, kstep of 64): rows [0,64): q*w_cq, [64,128): q*W3c0, [128,192):
// q*W3c1, 192: w_c, 193: W1c0, 194: W1c1. bf16, pitch 72, image 15360 shorts.
__global__ __launch_bounds__(256) void k_prep(
    const float* __restrict__ q, const float* __restrict__ w_cq,
    const float* __restrict__ w_c, const float* __restrict__ W_out,
    unsigned short* __restrict__ bpk) {
  const int s = blockIdx.x, b = blockIdx.y;
  const int k0 = s * 64;
  unsigned short* img = bpk + ((size_t)b * NIMG + s) * IMG;
  const int t = threadIdx.x;
#pragma unroll
  for (int i = 0; i < 4; ++i) {
    int idx = t + 256 * i;  // 0..1023
    int qi = idx >> 4, kc = (idx & 15) * 4;
    float4 qv = *(const float4*)(q + ((size_t)b * Q + qi) * D + k0 + kc);
    float4 wq = *(const float4*)(w_cq + k0 + kc);
    const float* wp = W_out + (size_t)(2 * D + k0 + kc) * 2;  // W3 rows
    float4 wa = *(const float4*)(wp);
    float4 wb = *(const float4*)(wp + 4);
    uint2 u;
    u.x = pkbf(qv.x * wq.x, qv.y * wq.y);
    u.y = pkbf(qv.z * wq.z, qv.w * wq.w);
    *(uint2*)(img + qi * PITCH + kc) = u;
    u.x = pkbf(qv.x * wa.x, qv.y * wa.z);
    u.y = pkbf(qv.z * wb.x, qv.w * wb.z);
    *(uint2*)(img + (64 + qi) * PITCH + kc) = u;
    u.x = pkbf(qv.x * wa.y, qv.y * wa.w);
    u.y = pkbf(qv.z * wb.y, qv.w * wb.w);
    *(uint2*)(img + (128 + qi) * PITCH + kc) = u;
  }
  if (t < 48) {  // stats rows 192..194
    int r = t >> 4, kc = (t & 15) * 4;
    uint2 u;
    if (r == 0) {
      float4 w = *(const float4*)(w_c + k0 + kc);
      u.x = pkbf(w.x, w.y);
      u.y = pkbf(w.z, w.w);
    } else {
      const float* wp = W_out + (size_t)(k0 + kc) * 2 + (r - 1);  // W1 col r-1
      u.x = pkbf(wp[0], wp[2]);
      u.y = pkbf(wp[4], wp[6]);
    }
    *(uint2*)(img + (192 + r) * PITCH + kc) = u;
  }
}

// ---------------- kernel 1: per (b,i) q stats: q.w_q, q.W2c0, q.W2c1 --------
__global__ __launch_bounds__(256) void k_qstats(
    const float* __restrict__ q, const float* __restrict__ w_q,
    const float* __restrict__ W_out, float* __restrict__ qstats) {
  int bi = blockIdx.x;
  const float* qrow = q + (size_t)bi * D;
  int t = threadIdx.x;
  float a0 = 0.f, a1 = 0.f, a2 = 0.f;
  for (int d = t * 4; d < D; d += 256 * 4) {
    float4 qv = *(const float4*)(qrow + d);
    float4 wq = *(const float4*)(w_q + d);
    const float* wp = W_out + (size_t)(D + d) * 2;
    float4 wa = *(const float4*)(wp);
    float4 wb = *(const float4*)(wp + 4);
    a0 += qv.x * wq.x + qv.y * wq.y + qv.z * wq.z + qv.w * wq.w;
    a1 += qv.x * wa.x + qv.y * wa.z + qv.z * wb.x + qv.w * wb.z;
    a2 += qv.x * wa.y + qv.y * wa.w + qv.z * wb.y + qv.w * wb.w;
  }
  for (int m = 1; m < 64; m <<= 1) {
    a0 += __shfl_xor(a0, m, 64);
    a1 += __shfl_xor(a1, m, 64);
    a2 += __shfl_xor(a2, m, 64);
  }
  __shared__ float red[3][4];
  int w = t >> 6, lane = t & 63;
  if (lane == 0) { red[0][w] = a0; red[1][w] = a1; red[2][w] = a2; }
  __syncthreads();
  if (t == 0) {
    qstats[bi * 3 + 0] = red[0][0] + red[0][1] + red[0][2] + red[0][3];
    qstats[bi * 3 + 1] = red[1][0] + red[1][1] + red[1][2] + red[1][3];
    qstats[bi * 3 + 2] = red[2][0] + red[2][1] + red[2][2] + red[2][3];
  }
}

// ---------------- kernel 2: split-K MFMA score GEMM -------------------------
// grid (C/MT=6, KC=8, B=16) = 768 blocks, 512 thr (8 waves).
// Wave wv: mh = wv>>2 owns 32 rows; ng = wv&3 owns N-frag group (4/3/3/3).
__global__ __launch_bounds__(512, 4) void k_score(
    const unsigned short* __restrict__ bpk, const float* __restrict__ c,
    float* __restrict__ S3) {
  const int t = threadIdx.x;
  const int lane = t & 63, wv = t >> 6;
  const int b = blockIdx.z, kc = blockIdx.y, r0 = blockIdx.x * MT;
  const int lr = lane & 15, lg = lane >> 4;
  const int mh = wv >> 2, ng = wv & 3;
  const int f0 = (ng == 0) ? 0 : (1 + 3 * ng);
  const int nf = (ng == 0) ? 4 : 3;

  __shared__ unsigned short sA[2][MT * PITCH];
  __shared__ unsigned short sB[2][IMG];

  const int arow = t >> 3, acb = (t & 7) * 8;
  const float* pA = c + ((size_t)b * C + r0 + arow) * D + kc * 256 + acb;
  const unsigned short* gB = bpk + ((size_t)b * NIMG + kc * 4) * IMG + lane * 8;

  f32x4 acc[2][4];
#pragma unroll
  for (int m = 0; m < 2; ++m)
#pragma unroll
    for (int f = 0; f < 4; ++f) acc[m][f] = f32x4{0.f, 0.f, 0.f, 0.f};

  auto stage = [&](int buf, int s) {
    const unsigned short* g = gB + (size_t)s * IMG;
#pragma unroll
    for (int i = 0; i < 4; ++i) {
      int cid = wv + 8 * i;  // 30 KB-chunks: waves 0..5 do 4, waves 6,7 do 3
      if (cid < 30)
        __builtin_amdgcn_global_load_lds(
            (const __attribute__((address_space(1))) unsigned*)(g + cid * 512),
            (__attribute__((address_space(3))) unsigned*)(&sB[buf][cid * 512]),
            16, 0, 0);
    }
  };
  float4 rE0, rE1, rO0, rO1;
  auto loadA = [&](float4& x, float4& y, int s) {
    const float* p = pA + s * 64;
    x = *(const float4*)(p);
    y = *(const float4*)(p + 4);
  };
  auto writeA = [&](int buf, const float4& x, const float4& y) {
    u32x4 u = {pkbf(x.x, x.y), pkbf(x.z, x.w), pkbf(y.x, y.y), pkbf(y.z, y.w)};
    *(u32x4*)(&sA[buf][arow * PITCH + acb]) = u;
  };
  auto compute = [&](int buf) {
#pragma unroll
    for (int h = 0; h < 2; ++h) {
      s16x8 af[2];
#pragma unroll
      for (int m = 0; m < 2; ++m)
        af[m] = *(const s16x8*)(&sA[buf][(mh * 32 + m * 16 + lr) * PITCH +
                                         h * 32 + lg * 8]);
#pragma unroll
      for (int f = 0; f < 4; ++f)
        if (f < nf) {
          s16x8 bf = *(const s16x8*)(&sB[buf][((f0 + f) * 16 + lr) * PITCH +
                                              h * 32 + lg * 8]);
#pragma unroll
          for (int m = 0; m < 2; ++m)
            acc[m][f] = __builtin_amdgcn_mfma_f32_16x16x32_bf16(
                af[m], bf, acc[m][f], 0, 0, 0);
        }
    }
  };

  loadA(rE0, rE1, 0);
  stage(0, 0);
#pragma unroll
  for (int s2 = 0; s2 < 2; ++s2) {
    __syncthreads();                 // buffers 0 free
    writeA(0, rE0, rE1);
    loadA(rO0, rO1, 2 * s2 + 1);
    stage(1, 2 * s2 + 1);
    asm volatile("s_waitcnt vmcnt(5)" ::: "memory");  // stage(0, 2*s2) landed
    __syncthreads();                 // publish buffers 0
    compute(0);
    __syncthreads();                 // buffers 1 free
    writeA(1, rO0, rO1);
    if (s2 < 1) {
      loadA(rE0, rE1, 2 * s2 + 2);
      stage(0, 2 * s2 + 2);
      asm volatile("s_waitcnt vmcnt(5)" ::: "memory");
    } else {
      asm volatile("s_waitcnt vmcnt(0)" ::: "memory");
    }
    __syncthreads();                 // publish buffers 1
    compute(1);
  }

  // epilogue: atomic accumulate into S3
  const size_t base = ((size_t)b * C + r0 + mh * 32) * SP;
#pragma unroll
  for (int m = 0; m < 2; ++m)
#pragma unroll
    for (int f = 0; f < 4; ++f)
      if (f < nf) {
        float* p =
            S3 + base + (size_t)(m * 16 + lg * 4) * SP + (f0 + f) * 16 + lr;
#pragma unroll
        for (int j = 0; j < 4; ++j) unsafeAtomicAdd(p + (size_t)j * SP, acc[m][f][j]);
      }
}

// ---------------- kernel 3: per-row softmax + reductions --------------------
// block 256 = 4 rows (wave per row); grid B*C/4 = 1536.
__global__ __launch_bounds__(256) void k_soft(
    const float* __restrict__ S3, const float* __restrict__ qstats,
    const int* __restrict__ c_len, const int* __restrict__ q_len,
    const float* __restrict__ b_c, const float* __restrict__ b_q,
    const float* __restrict__ b_cq, float* __restrict__ mrow,
    float* __restrict__ out12) {
  const int t = threadIdx.x, lane = t & 63;
  const int rg = blockIdx.x * 4 + (t >> 6);  // b*C + r
  const int b = rg / C, r = rg % C;
  const float* Sr = S3 + (size_t)rg * SP;
  const float qs0 = qstats[((b << 6) + lane) * 3 + 0];
  const float qs1 = qstats[((b << 6) + lane) * 3 + 1];
  const float qs2 = qstats[((b << 6) + lane) * 3 + 2];
  float s = Sr[lane] + Sr[192] + qs0 + b_c[0] + b_q[0] + b_cq[0];
  const int cl = c_len[b], ql = q_len[b];
  bool masked = (lane >= ql) || ((r >= cl) && (lane < Q - 1));
  if (masked) s += NEGV;
  float mx = s;
  for (int m = 1; m < 64; m <<= 1) mx = fmaxf(mx, __shfl_xor(mx, m, 64));
  float e = __expf(s - mx);
  float den = e;
  for (int m = 1; m < 64; m <<= 1) den += __shfl_xor(den, m, 64);
  float a = e / den;
  float v0 = a * (qs1 + Sr[64 + lane]);
  float v1 = a * (qs2 + Sr[128 + lane]);
  for (int m = 1; m < 64; m <<= 1) {
    v0 += __shfl_xor(v0, m, 64);
    v1 += __shfl_xor(v1, m, 64);
  }
  if (lane == 0) {
    mrow[rg] = mx;
    out12[rg * 2 + 0] = Sr[193] + v0;
    out12[rg * 2 + 1] = Sr[194] + v1;
  }
}

// ---------------- kernel 4: b_att softmax + q2c ------------------------------
__global__ __launch_bounds__(256) void k_q2c(const float* __restrict__ c,
                                             const float* __restrict__ mrow,
                                             float* __restrict__ q2c) {
  int b = blockIdx.y;
  int d0 = blockIdx.x * 128;
  int t = threadIdx.x;
  __shared__ float batt[C];
  __shared__ float red_mx[4];
  __shared__ float red_sm[4];
  __shared__ float part[128];

  float m1 = mrow[b * C + t];
  float m2 = (t < C - 256) ? mrow[b * C + 256 + t] : -3.0e38f;
  float mx = fmaxf(m1, m2);
  for (int m = 1; m < 64; m <<= 1) mx = fmaxf(mx, __shfl_xor(mx, m, 64));
  if ((t & 63) == 0) red_mx[t >> 6] = mx;
  __syncthreads();
  mx = fmaxf(fmaxf(red_mx[0], red_mx[1]), fmaxf(red_mx[2], red_mx[3]));
  float e1 = __expf(m1 - mx);
  float e2 = (t < C - 256) ? __expf(m2 - mx) : 0.f;
  float sum = e1 + e2;
  for (int m = 1; m < 64; m <<= 1) sum += __shfl_xor(sum, m, 64);
  if ((t & 63) == 0) red_sm[t >> 6] = sum;
  __syncthreads();
  sum = red_sm[0] + red_sm[1] + red_sm[2] + red_sm[3];
  batt[t] = e1 / sum;
  if (t < C - 256) batt[256 + t] = e2 / sum;
  __syncthreads();

  int dl = t & 127;
  int half = t >> 7;
  const float* cb = c + (size_t)b * C * D + d0 + dl;
  float acc = 0.f;
  for (int r = half * 192; r < half * 192 + 192; r++)
    acc += batt[r] * cb[(size_t)r * D];
  if (half == 1) part[dl] = acc;
  __syncthreads();
  if (half == 0) q2c[(size_t)b * D + d0 + dl] = acc + part[dl];
}

// ---------------- kernel 5: term4 + bias + final mask + write ---------------
__global__ __launch_bounds__(256) void k_out(
    const float* __restrict__ c, const float* __restrict__ q2c,
    const float* __restrict__ W_out, const float* __restrict__ b_out,
    const float* __restrict__ out12, const int* __restrict__ c_len,
    float* __restrict__ outp) {
  int idx = blockIdx.x;
  int b = idx / C, r = idx % C;
  const float* crow = c + (size_t)idx * D;
  const float* v = q2c + (size_t)b * D;
  int t = threadIdx.x;
  float a0 = 0.f, a1 = 0.f;
  for (int d = t * 4; d < D; d += 1024) {
    float4 cv = *(const float4*)(crow + d);
    float4 vv = *(const float4*)(v + d);
    const float* wp = W_out + (size_t)(3 * D + d) * 2;
    float4 wa = *(const float4*)(wp);
    float4 wb = *(const float4*)(wp + 4);
    float px = cv.x * vv.x, py = cv.y * vv.y;
    float pz = cv.z * vv.z, pw = cv.w * vv.w;
    a0 += px * wa.x + py * wa.z + pz * wb.x + pw * wb.z;
    a1 += px * wa.y + py * wa.w + pz * wb.y + pw * wb.w;
  }
  for (int m = 1; m < 64; m <<= 1) {
    a0 += __shfl_xor(a0, m, 64);
    a1 += __shfl_xor(a1, m, 64);
  }
  __shared__ float red[2][4];
  int w = t >> 6, lane = t & 63;
  if (lane == 0) { red[0][w] = a0; red[1][w] = a1; }
  __syncthreads();
  if (t == 0) {
    float o0 = out12[idx * 2 + 0] + red[0][0] + red[0][1] + red[0][2] +
               red[0][3] + b_out[0];
    float o1 = out12[idx * 2 + 1] + red[1][0] + red[1][1] + red[1][2] +
               red[1][3] + b_out[1];
    if (r >= c_len[b] && r < C - 1) { o0 = NEGV; o1 = NEGV; }
    outp[idx] = o0;
    outp[B * C + idx] = o1;
  }
}

extern "C" void kernel_launch(void* const* d_in, const int* in_sizes, int n_in,
                              void* d_out, int out_size, void* d_ws,
                              size_t ws_size, hipStream_t stream) {
  const float* c = (const float*)d_in[0];
  const float* q = (const float*)d_in[1];
  const int* c_len = (const int*)d_in[2];
  const int* q_len = (const int*)d_in[3];
  const float* w_c = (const float*)d_in[4];
  const float* b_c = (const float*)d_in[5];
  const float* w_q = (const float*)d_in[6];
  const float* b_q = (const float*)d_in[7];
  const float* w_cq = (const float*)d_in[8];
  const float* b_cq = (const float*)d_in[9];
  const float* W_out = (const float*)d_in[10];
  const float* b_out = (const float*)d_in[11];
  float* outp = (float*)d_out;

  // ws: bpk (15.73 MB) | S3 (5.51 MB) | small f32 buffers
  unsigned short* bpk = (unsigned short*)d_ws;
  const size_t bpk_bytes = (size_t)B * NIMG * IMG * 2;  // 15,728,640
  float* S3 = (float*)((char*)d_ws + bpk_bytes);
  const size_t s3_elems = (size_t)B * C * SP;           // 1,376,256
  float* ws = S3 + s3_elems;
  float* qstats = ws;                     // B*Q*3  = 3072
  float* mrow = ws + 3072;                // B*C    = 6144
  float* out12 = ws + 3072 + 6144;        // B*C*2  = 12288
  float* q2c = ws + 3072 + 6144 + 12288;  // B*D    = 32768

  hipMemsetAsync(S3, 0, s3_elems * 4, stream);
  hipLaunchKernelGGL(k_prep, dim3(NIMG, B), dim3(256), 0, stream, q, w_cq,
                     w_c, W_out, bpk);
  hipLaunchKernelGGL(k_qstats, dim3(B * Q), dim3(256), 0, stream, q, w_q,
                     W_out, qstats);
  hipLaunchKernelGGL(k_score, dim3(C / MT, 8, B), dim3(512), 0, stream, bpk,
                     c, S3);
  hipLaunchKernelGGL(k_soft, dim3(B * C / 4), dim3(256), 0, stream, S3,
                     qstats, c_len, q_len, b_c, b_q, b_cq, mrow, out12);
  hipLaunchKernelGGL(k_q2c, dim3(16, B), dim3(256), 0, stream, c, mrow, q2c);
  hipLaunchKernelGGL(k_out, dim3(B * C), dim3(256), 0, stream, c, q2c, W_out,
                     b_out, out12, c_len, outp);
}

// Round 5
// 70.666 us; speedup vs baseline: 1.3199x; 1.3199x over previous
//
#include <hip/hip_runtime.h>

#define NEGV -1.0e12f
constexpr int B = 16, C = 384, Q = 64, D = 2048;
constexpr int IMG = 15360;   // shorts per 64-k B-image (30720 B = 30 1KB-chunks)
constexpr int PITCH = 72;    // shorts per row (144 B, 16B-aligned, uniform banks)
constexpr int NIMG = 32;     // images per batch (D/64)
constexpr int MT = 64;       // c-rows per k_score block
constexpr int KC = 4;        // split-K chunks (512 k each, 8 images)
constexpr int SP = 208;      // S3 partial col pitch

typedef __attribute__((ext_vector_type(8))) short s16x8;
typedef __attribute__((ext_vector_type(4))) float f32x4;
typedef __attribute__((ext_vector_type(4))) unsigned u32x4;

__device__ __forceinline__ unsigned pkbf(float lo, float hi) {
  unsigned ulo = __builtin_bit_cast(unsigned, lo);
  unsigned uhi = __builtin_bit_cast(unsigned, hi);
  return (uhi & 0xFFFF0000u) | (ulo >> 16);
}

// ---------------- kernel 0: pre-pack B images into ws -----------------------
// Per (b, kstep of 64): rows [0,64): q*w_cq, [64,128): q*W3c0, [128,192):
// q*W3c1, 192: w_c, 193: W1c0, 194: W1c1. bf16, pitch 72, image 15360 shorts.
__global__ __launch_bounds__(256) void k_prep(
    const float* __restrict__ q, const float* __restrict__ w_cq,
    const float* __restrict__ w_c, const float* __restrict__ W_out,
    unsigned short* __restrict__ bpk) {
  const int s = blockIdx.x, b = blockIdx.y;
  const int k0 = s * 64;
  unsigned short* img = bpk + ((size_t)b * NIMG + s) * IMG;
  const int t = threadIdx.x;
#pragma unroll
  for (int i = 0; i < 4; ++i) {
    int idx = t + 256 * i;  // 0..1023
    int qi = idx >> 4, kc = (idx & 15) * 4;
    float4 qv = *(const float4*)(q + ((size_t)b * Q + qi) * D + k0 + kc);
    float4 wq = *(const float4*)(w_cq + k0 + kc);
    const float* wp = W_out + (size_t)(2 * D + k0 + kc) * 2;  // W3 rows
    float4 wa = *(const float4*)(wp);
    float4 wb = *(const float4*)(wp + 4);
    uint2 u;
    u.x = pkbf(qv.x * wq.x, qv.y * wq.y);
    u.y = pkbf(qv.z * wq.z, qv.w * wq.w);
    *(uint2*)(img + qi * PITCH + kc) = u;
    u.x = pkbf(qv.x * wa.x, qv.y * wa.z);
    u.y = pkbf(qv.z * wb.x, qv.w * wb.z);
    *(uint2*)(img + (64 + qi) * PITCH + kc) = u;
    u.x = pkbf(qv.x * wa.y, qv.y * wa.w);
    u.y = pkbf(qv.z * wb.y, qv.w * wb.w);
    *(uint2*)(img + (128 + qi) * PITCH + kc) = u;
  }
  if (t < 48) {  // stats rows 192..194
    int r = t >> 4, kc = (t & 15) * 4;
    uint2 u;
    if (r == 0) {
      float4 w = *(const float4*)(w_c + k0 + kc);
      u.x = pkbf(w.x, w.y);
      u.y = pkbf(w.z, w.w);
    } else {
      const float* wp = W_out + (size_t)(k0 + kc) * 2 + (r - 1);  // W1 col r-1
      u.x = pkbf(wp[0], wp[2]);
      u.y = pkbf(wp[4], wp[6]);
    }
    *(uint2*)(img + (192 + r) * PITCH + kc) = u;
  }
}

// ---------------- kernel 1: per (b,i) q stats: q.w_q, q.W2c0, q.W2c1 --------
__global__ __launch_bounds__(256) void k_qstats(
    const float* __restrict__ q, const float* __restrict__ w_q,
    const float* __restrict__ W_out, float* __restrict__ qstats) {
  int bi = blockIdx.x;
  const float* qrow = q + (size_t)bi * D;
  int t = threadIdx.x;
  float a0 = 0.f, a1 = 0.f, a2 = 0.f;
  for (int d = t * 4; d < D; d += 256 * 4) {
    float4 qv = *(const float4*)(qrow + d);
    float4 wq = *(const float4*)(w_q + d);
    const float* wp = W_out + (size_t)(D + d) * 2;
    float4 wa = *(const float4*)(wp);
    float4 wb = *(const float4*)(wp + 4);
    a0 += qv.x * wq.x + qv.y * wq.y + qv.z * wq.z + qv.w * wq.w;
    a1 += qv.x * wa.x + qv.y * wa.z + qv.z * wb.x + qv.w * wb.z;
    a2 += qv.x * wa.y + qv.y * wa.w + qv.z * wb.y + qv.w * wb.w;
  }
  for (int m = 1; m < 64; m <<= 1) {
    a0 += __shfl_xor(a0, m, 64);
    a1 += __shfl_xor(a1, m, 64);
    a2 += __shfl_xor(a2, m, 64);
  }
  __shared__ float red[3][4];
  int w = t >> 6, lane = t & 63;
  if (lane == 0) { red[0][w] = a0; red[1][w] = a1; red[2][w] = a2; }
  __syncthreads();
  if (t == 0) {
    qstats[bi * 3 + 0] = red[0][0] + red[0][1] + red[0][2] + red[0][3];
    qstats[bi * 3 + 1] = red[1][0] + red[1][1] + red[1][2] + red[1][3];
    qstats[bi * 3 + 2] = red[2][0] + red[2][1] + red[2][2] + red[2][3];
  }
}

// ---------------- kernel 2: split-K MFMA score GEMM (no atomics) ------------
// grid (C/MT=6, KC=4, B=16) = 384 blocks, 512 thr (8 waves = 4m x 2n).
// A direct global->reg->bf16; B glds-staged double-buffer; 1 barrier/step.
__global__ __launch_bounds__(512, 4) void k_score(
    const unsigned short* __restrict__ bpk, const float* __restrict__ c,
    float* __restrict__ S3p) {
  const int t = threadIdx.x;
  const int lane = t & 63, wv = t >> 6;
  const int b = blockIdx.z, kcb = blockIdx.y, r0 = blockIdx.x * MT;
  const int lr = lane & 15, lg = lane >> 4;
  const int mg = wv >> 1, ng = wv & 1;
  const int f0 = ng * 7;
  const int nf = ng ? 6 : 7;

  __shared__ unsigned short sB[2][IMG];

  const float* pA =
      c + ((size_t)b * C + r0 + mg * 16 + lr) * D + kcb * 512 + lg * 8;
  const unsigned short* gB =
      bpk + ((size_t)b * NIMG + kcb * 8) * IMG + lane * 8;

  f32x4 acc[7];
#pragma unroll
  for (int f = 0; f < 7; ++f) acc[f] = f32x4{0.f, 0.f, 0.f, 0.f};

  auto stage = [&](int buf, int s) {
    const unsigned short* g = gB + (size_t)s * IMG;
#pragma unroll
    for (int i = 0; i < 4; ++i) {
      int cid = wv + 8 * i;  // 30 chunks: waves 0..5 do 4, waves 6,7 do 3
      if (cid < 30)
        __builtin_amdgcn_global_load_lds(
            (const __attribute__((address_space(1))) unsigned*)(g + cid * 512),
            (__attribute__((address_space(3))) unsigned*)(&sB[buf][cid * 512]),
            16, 0, 0);
    }
  };
  auto loadA = [&](float4* r, int s) {
    const float* p = pA + s * 64;
    r[0] = *(const float4*)(p);
    r[1] = *(const float4*)(p + 4);
    r[2] = *(const float4*)(p + 32);
    r[3] = *(const float4*)(p + 36);
  };
  auto compute = [&](int buf, const float4* r) {
#pragma unroll
    for (int h = 0; h < 2; ++h) {
      float4 lo = r[2 * h], hi = r[2 * h + 1];
      u32x4 au = {pkbf(lo.x, lo.y), pkbf(lo.z, lo.w), pkbf(hi.x, hi.y),
                  pkbf(hi.z, hi.w)};
      s16x8 af = __builtin_bit_cast(s16x8, au);
#pragma unroll
      for (int f = 0; f < 7; ++f)
        if (f < nf) {
          s16x8 bf = *(const s16x8*)(&sB[buf][((f0 + f) * 16 + lr) * PITCH +
                                              h * 32 + lg * 8]);
          acc[f] =
              __builtin_amdgcn_mfma_f32_16x16x32_bf16(af, bf, acc[f], 0, 0, 0);
        }
    }
  };

  float4 rA[2][4];
  stage(0, 0);       // glds oldest in vm queue
  loadA(rA[0], 0);
#pragma unroll
  for (int s = 0; s < 8; ++s) {
    // wait this step's B-stage glds (4 oldest); A loads (4 newest) may float
    asm volatile("s_waitcnt vmcnt(4)" ::: "memory");
    __syncthreads();  // publish sB[s&1]; all waves done reading sB[(s+1)&1]
    if (s < 7) {
      stage((s + 1) & 1, s + 1);
      loadA(rA[(s + 1) & 1], s + 1);
    }
    compute(s & 1, rA[s & 1]);
  }

  // epilogue: plain stores to this kc-chunk's partial buffer
  const size_t rbase = ((size_t)kcb * B + b) * C + r0 + mg * 16 + lg * 4;
#pragma unroll
  for (int f = 0; f < 7; ++f)
    if (f < nf) {
      float* p = S3p + rbase * SP + (f0 + f) * 16 + lr;
#pragma unroll
      for (int j = 0; j < 4; ++j) p[(size_t)j * SP] = acc[f][j];
    }
}

// ---------------- kernel 3: sum partials + row softmax + reductions ---------
// block 256 = 4 rows (wave per row); grid B*C/4 = 1536.
__global__ __launch_bounds__(256) void k_soft(
    const float* __restrict__ S3p, const float* __restrict__ qstats,
    const int* __restrict__ c_len, const int* __restrict__ q_len,
    const float* __restrict__ b_c, const float* __restrict__ b_q,
    const float* __restrict__ b_cq, float* __restrict__ mrow,
    float* __restrict__ out12) {
  const int t = threadIdx.x, lane = t & 63;
  const int rg = blockIdx.x * 4 + (t >> 6);  // b*C + r
  const int b = rg / C, r = rg % C;
  float s_cq = 0.f, sc = 0.f, w10 = 0.f, w11 = 0.f, t30 = 0.f, t31 = 0.f;
#pragma unroll
  for (int p = 0; p < KC; ++p) {
    const float* Sr = S3p + ((size_t)p * B * C + rg) * SP;
    s_cq += Sr[lane];
    sc += Sr[192];
    w10 += Sr[193];
    w11 += Sr[194];
    t30 += Sr[64 + lane];
    t31 += Sr[128 + lane];
  }
  const float qs0 = qstats[((b << 6) + lane) * 3 + 0];
  const float qs1 = qstats[((b << 6) + lane) * 3 + 1];
  const float qs2 = qstats[((b << 6) + lane) * 3 + 2];
  float s = s_cq + sc + qs0 + b_c[0] + b_q[0] + b_cq[0];
  const int cl = c_len[b], ql = q_len[b];
  bool masked = (lane >= ql) || ((r >= cl) && (lane < Q - 1));
  if (masked) s += NEGV;
  float mx = s;
  for (int m = 1; m < 64; m <<= 1) mx = fmaxf(mx, __shfl_xor(mx, m, 64));
  float e = __expf(s - mx);
  float den = e;
  for (int m = 1; m < 64; m <<= 1) den += __shfl_xor(den, m, 64);
  float a = e / den;
  float v0 = a * (qs1 + t30);
  float v1 = a * (qs2 + t31);
  for (int m = 1; m < 64; m <<= 1) {
    v0 += __shfl_xor(v0, m, 64);
    v1 += __shfl_xor(v1, m, 64);
  }
  if (lane == 0) {
    mrow[rg] = mx;
    out12[rg * 2 + 0] = w10 + v0;
    out12[rg * 2 + 1] = w11 + v1;
  }
}

// ---------------- kernel 4: b_att softmax + q2c ------------------------------
__global__ __launch_bounds__(256) void k_q2c(const float* __restrict__ c,
                                             const float* __restrict__ mrow,
                                             float* __restrict__ q2c) {
  int b = blockIdx.y;
  int d0 = blockIdx.x * 128;
  int t = threadIdx.x;
  __shared__ float batt[C];
  __shared__ float red_mx[4];
  __shared__ float red_sm[4];
  __shared__ float part[128];

  float m1 = mrow[b * C + t];
  float m2 = (t < C - 256) ? mrow[b * C + 256 + t] : -3.0e38f;
  float mx = fmaxf(m1, m2);
  for (int m = 1; m < 64; m <<= 1) mx = fmaxf(mx, __shfl_xor(mx, m, 64));
  if ((t & 63) == 0) red_mx[t >> 6] = mx;
  __syncthreads();
  mx = fmaxf(fmaxf(red_mx[0], red_mx[1]), fmaxf(red_mx[2], red_mx[3]));
  float e1 = __expf(m1 - mx);
  float e2 = (t < C - 256) ? __expf(m2 - mx) : 0.f;
  float sum = e1 + e2;
  for (int m = 1; m < 64; m <<= 1) sum += __shfl_xor(sum, m, 64);
  if ((t & 63) == 0) red_sm[t >> 6] = sum;
  __syncthreads();
  sum = red_sm[0] + red_sm[1] + red_sm[2] + red_sm[3];
  batt[t] = e1 / sum;
  if (t < C - 256) batt[256 + t] = e2 / sum;
  __syncthreads();

  int dl = t & 127;
  int half = t >> 7;
  const float* cb = c + (size_t)b * C * D + d0 + dl;
  float acc = 0.f;
  for (int r = half * 192; r < half * 192 + 192; r++)
    acc += batt[r] * cb[(size_t)r * D];
  if (half == 1) part[dl] = acc;
  __syncthreads();
  if (half == 0) q2c[(size_t)b * D + d0 + dl] = acc + part[dl];
}

// ---------------- kernel 5: term4 + bias + final mask + write ---------------
__global__ __launch_bounds__(256) void k_out(
    const float* __restrict__ c, const float* __restrict__ q2c,
    const float* __restrict__ W_out, const float* __restrict__ b_out,
    const float* __restrict__ out12, const int* __restrict__ c_len,
    float* __restrict__ outp) {
  int idx = blockIdx.x;
  int b = idx / C, r = idx % C;
  const float* crow = c + (size_t)idx * D;
  const float* v = q2c + (size_t)b * D;
  int t = threadIdx.x;
  float a0 = 0.f, a1 = 0.f;
  for (int d = t * 4; d < D; d += 1024) {
    float4 cv = *(const float4*)(crow + d);
    float4 vv = *(const float4*)(v + d);
    const float* wp = W_out + (size_t)(3 * D + d) * 2;
    float4 wa = *(const float4*)(wp);
    float4 wb = *(const float4*)(wp + 4);
    float px = cv.x * vv.x, py = cv.y * vv.y;
    float pz = cv.z * vv.z, pw = cv.w * vv.w;
    a0 += px * wa.x + py * wa.z + pz * wb.x + pw * wb.z;
    a1 += px * wa.y + py * wa.w + pz * wb.y + pw * wb.w;
  }
  for (int m = 1; m < 64; m <<= 1) {
    a0 += __shfl_xor(a0, m, 64);
    a1 += __shfl_xor(a1, m, 64);
  }
  __shared__ float red[2][4];
  int w = t >> 6, lane = t & 63;
  if (lane == 0) { red[0][w] = a0; red[1][w] = a1; }
  __syncthreads();
  if (t == 0) {
    float o0 = out12[idx * 2 + 0] + red[0][0] + red[0][1] + red[0][2] +
               red[0][3] + b_out[0];
    float o1 = out12[idx * 2 + 1] + red[1][0] + red[1][1] + red[1][2] +
               red[1][3] + b_out[1];
    if (r >= c_len[b] && r < C - 1) { o0 = NEGV; o1 = NEGV; }
    outp[idx] = o0;
    outp[B * C + idx] = o1;
  }
}

extern "C" void kernel_launch(void* const* d_in, const int* in_sizes, int n_in,
                              void* d_out, int out_size, void* d_ws,
                              size_t ws_size, hipStream_t stream) {
  const float* c = (const float*)d_in[0];
  const float* q = (const float*)d_in[1];
  const int* c_len = (const int*)d_in[2];
  const int* q_len = (const int*)d_in[3];
  const float* w_c = (const float*)d_in[4];
  const float* b_c = (const float*)d_in[5];
  const float* w_q = (const float*)d_in[6];
  const float* b_q = (const float*)d_in[7];
  const float* w_cq = (const float*)d_in[8];
  const float* b_cq = (const float*)d_in[9];
  const float* W_out = (const float*)d_in[10];
  const float* b_out = (const float*)d_in[11];
  float* outp = (float*)d_out;

  // ws: bpk (15.73 MB) | S3 partials (20.45 MB) | small f32 buffers
  unsigned short* bpk = (unsigned short*)d_ws;
  const size_t bpk_bytes = (size_t)B * NIMG * IMG * 2;  // 15,728,640
  float* S3p = (float*)((char*)d_ws + bpk_bytes);
  const size_t s3_elems = (size_t)KC * B * C * SP;      // 5,111,808
  float* ws = S3p + s3_elems;
  float* qstats = ws;                     // B*Q*3  = 3072
  float* mrow = ws + 3072;                // B*C    = 6144
  float* out12 = ws + 3072 + 6144;        // B*C*2  = 12288
  float* q2c = ws + 3072 + 6144 + 12288;  // B*D    = 32768

  hipLaunchKernelGGL(k_prep, dim3(NIMG, B), dim3(256), 0, stream, q, w_cq,
                     w_c, W_out, bpk);
  hipLaunchKernelGGL(k_qstats, dim3(B * Q), dim3(256), 0, stream, q, w_q,
                     W_out, qstats);
  hipLaunchKernelGGL(k_score, dim3(C / MT, KC, B), dim3(512), 0, stream, bpk,
                     c, S3p);
  hipLaunchKernelGGL(k_soft, dim3(B * C / 4), dim3(256), 0, stream, S3p,
                     qstats, c_len, q_len, b_c, b_q, b_cq, mrow, out12);
  hipLaunchKernelGGL(k_q2c, dim3(16, B), dim3(256), 0, stream, c, mrow, q2c);
  hipLaunchKernelGGL(k_out, dim3(B * C), dim3(256), 0, stream, c, q2c, W_out,
                     b_out, out12, c_len, outp);
}